// Round 5
// baseline (263.553 us; speedup 1.0000x reference)
//
#include <hip/hip_runtime.h>
#include <math.h>

#define N_PIX (1024 * 1024)
#define NSEG 1024
#define NCH 32
#define NCHUNK 16
#define NEDGE 8192
#define EPS 1e-8f
#define INV_TAU 2.0f
// Fixed-point scale for int32 LDS histogram accumulation (round-4 verified:
// absmax 0.0 vs ref). Per-(chunk,segment) partial |sum| <= ~few hundred
// (uniform random seg: ~64 px/seg/chunk); 2^31/2^18 = 8192 bound, >10x margin.
#define SCALE 262144.0f
#define INV_SCALE (1.0f / 262144.0f)

// ws layout (4-byte units). Every region fully written before read each launch
// (plain stores, no accumulation, no atomics) -> no memset, deterministic.
#define OFF_GSUMI 0                                    // int  [16][32][1024]
#define OFF_GCNTI (OFF_GSUMI + NCHUNK * NCH * NSEG)    // int  [16][16][1024]
#define OFF_MEANSN (OFF_GCNTI + NCHUNK * 16 * NSEG)    // float[1024][32] normalized means
#define OFF_BPE (OFF_MEANSN + NSEG * NCH)              // float[512] per-block sum(exp(intra))
#define OFF_BPI (OFF_BPE + 512)                        // float[512] per-block sum(intra)
#define OFF_IPE (OFF_BPI + 512)                        // float[32]  per-block sum(exp(inter))

// ---------------------------------------------------------------------------
// Kernel 1: per-segment sums, int fixed-point LDS histogram (native
// ds_add_u32; float atomics = serialized CAS path, rounds 1-3 A/B).
// 512 blocks = 32 channels x 16 pixel chunks, 1024 thr -> 2 blocks/CU,
// 32 waves/CU (round 4 ran 16 waves/CU, latency-bound at 211 GB/s).
// bid = c*16 + j -> bid%8 = j%8: all 32 channel-blocks of chunk j on one
// XCD (seg slice L2-shared). Count duty: block (j,c) counts iteration
// it==c (c<16) -> each pixel counted exactly once, balanced.
// ---------------------------------------------------------------------------
__global__ __launch_bounds__(1024) void k_segsum(const float* __restrict__ emb,
                                                 const int* __restrict__ seg,
                                                 int* __restrict__ gsum_i,
                                                 int* __restrict__ gcnt_i) {
    __shared__ int lsum[NSEG];
    __shared__ int lcnt[NSEG];
    const int bid = blockIdx.x;
    const int c = bid >> 4;   // channel 0..31
    const int j = bid & 15;   // pixel chunk 0..15
    const int t = threadIdx.x;

    lsum[t] = 0;
    lcnt[t] = 0;
    __syncthreads();

    const int chunk = N_PIX / NCHUNK;  // 65536 pixels
    const float* ec = emb + (size_t)c * N_PIX + (size_t)j * chunk;
    const int* sg = seg + j * chunk;

    // 16 iterations: 1024 threads * 4 pixels each
    for (int it = 0; it < chunk / (1024 * 4); ++it) {
        const int idx = (it * 1024 + t) * 4;
        const float4 v = *(const float4*)(ec + idx);
        const int4 s4 = *(const int4*)(sg + idx);
        atomicAdd(&lsum[s4.x], __float2int_rn(v.x * SCALE));
        atomicAdd(&lsum[s4.y], __float2int_rn(v.y * SCALE));
        atomicAdd(&lsum[s4.z], __float2int_rn(v.z * SCALE));
        atomicAdd(&lsum[s4.w], __float2int_rn(v.w * SCALE));
        if (it == c) {  // only c<16 ever matches; each pixel counted once
            atomicAdd(&lcnt[s4.x], 1);
            atomicAdd(&lcnt[s4.y], 1);
            atomicAdd(&lcnt[s4.z], 1);
            atomicAdd(&lcnt[s4.w], 1);
        }
    }
    __syncthreads();

    gsum_i[(j * NCH + c) * NSEG + t] = lsum[t];  // block-owned slab, plain store
    if (c < 16) gcnt_i[(j * 16 + c) * NSEG + t] = lcnt[t];
}

// ---------------------------------------------------------------------------
// Kernel 2: combine int partials (exact) -> NORMALIZED means
// meansn[s][c] = (sum/cnt) / max(||mean||, eps). Folding the norm here
// removes the random mn[] gathers from k_intra and simplifies k_inter to a
// plain dot. 4 blocks x 256 threads, thread per segment, coalesced loads.
// ---------------------------------------------------------------------------
__global__ void k_means(const int* __restrict__ gsum_i,
                        const int* __restrict__ gcnt_i,
                        float* __restrict__ meansn) {
    const int s = blockIdx.x * 256 + threadIdx.x;
    int cnt_i = 0;
#pragma unroll 16
    for (int p = 0; p < NCHUNK * 16; ++p) cnt_i += gcnt_i[p * NSEG + s];
    const float inv = 1.0f / fmaxf((float)cnt_i, 1.0f);
    float m[NCH];
    float nrm = 0.0f;
#pragma unroll
    for (int c = 0; c < NCH; ++c) {
        int a = 0;
#pragma unroll
        for (int j = 0; j < NCHUNK; ++j) a += gsum_i[(j * NCH + c) * NSEG + s];
        m[c] = (float)a * INV_SCALE * inv;
        nrm += m[c] * m[c];
    }
    const float rn = 1.0f / fmaxf(sqrtf(nrm), EPS);
#pragma unroll
    for (int c = 0; c < NCH; ++c) meansn[s * NCH + c] = m[c] * rn;
}

// ---------------------------------------------------------------------------
// Kernel 3: per-pixel intra = dot(meansn[seg], e)/max(||e||,eps) * 2.
// 512 blocks x 512 threads x 4 px -> 4 blocks/CU, 32 waves/CU.
// Per-block partials as plain stores.
// ---------------------------------------------------------------------------
__global__ __launch_bounds__(512) void k_intra(const float* __restrict__ emb,
                                               const int* __restrict__ seg,
                                               const float* __restrict__ meansn,
                                               float* __restrict__ bpe,
                                               float* __restrict__ bpi) {
    const int g = blockIdx.x * 512 + threadIdx.x;
    const int n0 = g * 4;
    const int4 s4 = *(const int4*)(seg + n0);

    float dot0 = 0.f, dot1 = 0.f, dot2 = 0.f, dot3 = 0.f;
    float nr0 = 0.f, nr1 = 0.f, nr2 = 0.f, nr3 = 0.f;

#pragma unroll
    for (int c0 = 0; c0 < NCH; c0 += 4) {
        const float4 e0 = *(const float4*)(emb + (size_t)(c0 + 0) * N_PIX + n0);
        const float4 e1 = *(const float4*)(emb + (size_t)(c0 + 1) * N_PIX + n0);
        const float4 e2 = *(const float4*)(emb + (size_t)(c0 + 2) * N_PIX + n0);
        const float4 e3 = *(const float4*)(emb + (size_t)(c0 + 3) * N_PIX + n0);
        const float4 m0 = *(const float4*)(meansn + s4.x * NCH + c0);
        const float4 m1 = *(const float4*)(meansn + s4.y * NCH + c0);
        const float4 m2 = *(const float4*)(meansn + s4.z * NCH + c0);
        const float4 m3 = *(const float4*)(meansn + s4.w * NCH + c0);

        dot0 += m0.x * e0.x + m0.y * e1.x + m0.z * e2.x + m0.w * e3.x;
        dot1 += m1.x * e0.y + m1.y * e1.y + m1.z * e2.y + m1.w * e3.y;
        dot2 += m2.x * e0.z + m2.y * e1.z + m2.z * e2.z + m2.w * e3.z;
        dot3 += m3.x * e0.w + m3.y * e1.w + m3.z * e2.w + m3.w * e3.w;

        nr0 += e0.x * e0.x + e1.x * e1.x + e2.x * e2.x + e3.x * e3.x;
        nr1 += e0.y * e0.y + e1.y * e1.y + e2.y * e2.y + e3.y * e3.y;
        nr2 += e0.z * e0.z + e1.z * e1.z + e2.z * e2.z + e3.z * e3.z;
        nr3 += e0.w * e0.w + e1.w * e1.w + e2.w * e2.w + e3.w * e3.w;
    }

    const float i0 = dot0 / fmaxf(sqrtf(nr0), EPS) * INV_TAU;
    const float i1 = dot1 / fmaxf(sqrtf(nr1), EPS) * INV_TAU;
    const float i2 = dot2 / fmaxf(sqrtf(nr2), EPS) * INV_TAU;
    const float i3 = dot3 / fmaxf(sqrtf(nr3), EPS) * INV_TAU;
    float esum = expf(i0) + expf(i1) + expf(i2) + expf(i3);
    float isum = i0 + i1 + i2 + i3;

#pragma unroll
    for (int off = 32; off > 0; off >>= 1) {
        esum += __shfl_down(esum, off);
        isum += __shfl_down(isum, off);
    }
    __shared__ float we[8], wi[8];
    const int wid = threadIdx.x >> 6;
    const int lane = threadIdx.x & 63;
    if (lane == 0) { we[wid] = esum; wi[wid] = isum; }
    __syncthreads();
    if (threadIdx.x == 0) {
        float a = 0.f, b = 0.f;
#pragma unroll
        for (int w = 0; w < 8; ++w) { a += we[w]; b += wi[w]; }
        bpe[blockIdx.x] = a;
        bpi[blockIdx.x] = b;
    }
}

// ---------------------------------------------------------------------------
// Kernel 4: inter edges — exp(2 * dot(meansn[a], meansn[b])); partial store.
// ---------------------------------------------------------------------------
__global__ void k_inter(const int* __restrict__ edges,
                        const float* __restrict__ meansn,
                        float* __restrict__ ipe) {
    const int e = blockIdx.x * 256 + threadIdx.x;
    const int a = edges[e];
    const int b = edges[NEDGE + e];
    float dot = 0.0f;
#pragma unroll
    for (int c0 = 0; c0 < NCH; c0 += 4) {
        const float4 ma = *(const float4*)(meansn + a * NCH + c0);
        const float4 mb = *(const float4*)(meansn + b * NCH + c0);
        dot += ma.x * mb.x + ma.y * mb.y + ma.z * mb.z + ma.w * mb.w;
    }
    float ex = expf(dot * INV_TAU);
#pragma unroll
    for (int off = 32; off > 0; off >>= 1) ex += __shfl_down(ex, off);
    __shared__ float we[4];
    const int wid = threadIdx.x >> 6;
    const int lane = threadIdx.x & 63;
    if (lane == 0) we[wid] = ex;
    __syncthreads();
    if (threadIdx.x == 0) ipe[blockIdx.x] = we[0] + we[1] + we[2] + we[3];
}

// ---------------------------------------------------------------------------
// Kernel 5: reduce 512 intra partials + 32 inter partials ->
// out = log(sum_exp) - sum_intra / N. One 512-thread block, deterministic.
// ---------------------------------------------------------------------------
__global__ void k_final(const float* __restrict__ bpe,
                        const float* __restrict__ bpi,
                        const float* __restrict__ ipe,
                        float* __restrict__ out) {
    const int t = threadIdx.x;  // 512
    float e = bpe[t] + (t < 32 ? ipe[t] : 0.0f);
    float i = bpi[t];
#pragma unroll
    for (int off = 32; off > 0; off >>= 1) {
        e += __shfl_down(e, off);
        i += __shfl_down(i, off);
    }
    __shared__ float we[8], wi[8];
    const int wid = t >> 6;
    const int lane = t & 63;
    if (lane == 0) { we[wid] = e; wi[wid] = i; }
    __syncthreads();
    if (t == 0) {
        float E = 0.f, I = 0.f;
#pragma unroll
        for (int w = 0; w < 8; ++w) { E += we[w]; I += wi[w]; }
        out[0] = logf(E) - I * (1.0f / (float)N_PIX);
    }
}

extern "C" void kernel_launch(void* const* d_in, const int* in_sizes, int n_in,
                              void* d_out, int out_size, void* d_ws, size_t ws_size,
                              hipStream_t stream) {
    (void)in_sizes; (void)n_in; (void)out_size; (void)ws_size;
    const float* emb = (const float*)d_in[0];   // (32, 1024*1024) channel-major
    const int* seg = (const int*)d_in[1];       // (1024*1024,)
    const int* edges = (const int*)d_in[2];     // (2, 8192)
    float* out = (float*)d_out;

    int* wsi = (int*)d_ws;
    float* wsf = (float*)d_ws;
    int* gsum_i = wsi + OFF_GSUMI;
    int* gcnt_i = wsi + OFF_GCNTI;
    float* meansn = wsf + OFF_MEANSN;
    float* bpe = wsf + OFF_BPE;
    float* bpi = wsf + OFF_BPI;
    float* ipe = wsf + OFF_IPE;

    k_segsum<<<512, 1024, 0, stream>>>(emb, seg, gsum_i, gcnt_i);
    k_means<<<4, 256, 0, stream>>>(gsum_i, gcnt_i, meansn);
    k_intra<<<512, 512, 0, stream>>>(emb, seg, meansn, bpe, bpi);
    k_inter<<<NEDGE / 256, 256, 0, stream>>>(edges, meansn, ipe);
    k_final<<<1, 512, 0, stream>>>(bpe, bpi, ipe, out);
}